// Round 7
// baseline (89.473 us; speedup 1.0000x reference)
//
#include <hip/hip_runtime.h>
#include <math.h>

#define NB 16
#define NC 256
#define NH 64
#define NW 64
#define HALF 128
#define PLANE (NH*NW)   // 4096

// ws float layout
#define WS_WW   0       // 256: softmax(dir_weight_w)
#define WS_WH   256     // 256: softmax(dir_weight_h)
#define WS_GH   512     // NB*NH = 1024
#define WS_GW   1536    // NB*NW = 1024
#define WS_CONS 2560    // NB*NH*NW = 65536
#define WS_TOTAL 68096  // WS_GH + 66*256*4 floats

__device__ __forceinline__ float sum4(float4 v) { return (v.x+v.y)+(v.z+v.w); }

// blocks 0..65: zero gh/gw/cons (66*256 float4 = 67584 floats exactly).
// block 66: both channel softmaxes.
__global__ __launch_bounds__(256) void k_init(const float* __restrict__ dwh,
                                              const float* __restrict__ dww,
                                              float* __restrict__ ws) {
    const int t = threadIdx.x;
    if (blockIdx.x < 66) {
        float4 z = {0.f,0.f,0.f,0.f};
        reinterpret_cast<float4*>(ws + WS_GH)[blockIdx.x*256 + t] = z;
        return;
    }
    __shared__ float red[256];
    const float vh = dwh[t];
    const float vw = dww[t];

    red[t] = vw; __syncthreads();
    for (int s = 128; s > 0; s >>= 1) { if (t < s) red[t] = fmaxf(red[t], red[t+s]); __syncthreads(); }
    const float mw = red[0]; __syncthreads();
    const float ew = expf(vw - mw);
    red[t] = ew; __syncthreads();
    for (int s = 128; s > 0; s >>= 1) { if (t < s) red[t] += red[t+s]; __syncthreads(); }
    const float sw = red[0]; __syncthreads();
    ws[WS_WW + t] = ew / sw;

    red[t] = vh; __syncthreads();
    for (int s = 128; s > 0; s >>= 1) { if (t < s) red[t] = fmaxf(red[t], red[t+s]); __syncthreads(); }
    const float mh = red[0]; __syncthreads();
    const float eh = expf(vh - mh);
    red[t] = eh; __syncthreads();
    for (int s = 128; s > 0; s >>= 1) { if (t < s) red[t] += red[t+s]; __syncthreads(); }
    const float sh = red[0]; __syncthreads();
    ws[WS_WH + t] = eh / sh;
}

// Block = (b, 16-row stripe, group of 4 channel pairs). 2048 blocks.
// Wave = row-group (4 rows). Lane = fc(4b)<<2 | pl(2b).
// All global loads issued up-front, compiler barrier pins them in flight
// together (10-deep MLP). Interior vertical-halo prod rows exchanged via LDS;
// only edge waves load 2 extra global rows. cons via direct atomics.
__global__ __launch_bounds__(256) void k_reduce(const float* __restrict__ x,
                                                float* __restrict__ ws) {
    __shared__ float4 xch[4][2][64];   // prod rows 0 and 3 per row-group, 8 KB
    __shared__ float4 ldsc[4][16];     // gw staging, 1 KB

    const int t    = threadIdx.x;
    const int rg   = t >> 6;        // wave id = row group 0..3
    const int lane = t & 63;
    const int pl   = lane & 3;      // channel-pair lane
    const int fc   = lane >> 2;     // float4 col 0..15

    const int blk    = blockIdx.x;
    const int pg     = blk & 31;
    const int stripe = (blk >> 5) & 3;
    const int b      = blk >> 7;

    const int c1 = pg*4 + pl;
    const int c2 = c1 + HALF;
    const int r0 = stripe*16 + rg*4;     // first owned row

    const float ww1 = ws[WS_WW + c1], ww2 = ws[WS_WW + c2];
    const float wh1 = ws[WS_WH + c1], wh2 = ws[WS_WH + c2];

    const float* p1 = x + ((size_t)(b*NC + c1)) * PLANE;
    const float* p2 = x + ((size_t)(b*NC + c2)) * PLANE;

    // ---- load phase: 8 owned + (edge waves) 2 halo loads, all issued together
    float4 a[4], bb[4];
    #pragma unroll
    for (int j = 0; j < 4; ++j) {
        a[j]  = *(reinterpret_cast<const float4*>(p1 + (r0 + j)*NW) + fc);
        bb[j] = *(reinterpret_cast<const float4*>(p2 + (r0 + j)*NW) + fc);
    }
    const bool top = (rg == 0), bot = (rg == 3);
    float4 ea = {0.f,0.f,0.f,0.f}, eb = {0.f,0.f,0.f,0.f};
    if (top || bot) {                       // wave-uniform branch
        int er = top ? r0 - 1 : r0 + 4;
        er = er < 0 ? 0 : (er > 63 ? 63 : er);
        ea = *(reinterpret_cast<const float4*>(p1 + er*NW) + fc);
        eb = *(reinterpret_cast<const float4*>(p2 + er*NW) + fc);
    }
    asm volatile("" ::: "memory");   // pin all loads before any consumption

    // ---- linear reductions (gh / gw)
    float ghrow[4];
    float4 colacc = {0.f,0.f,0.f,0.f};
    #pragma unroll
    for (int j = 0; j < 4; ++j) {
        ghrow[j] = ww1*sum4(a[j]) + ww2*sum4(bb[j]);
        colacc.x += wh1*a[j].x + wh2*bb[j].x;
        colacc.y += wh1*a[j].y + wh2*bb[j].y;
        colacc.z += wh1*a[j].z + wh2*bb[j].z;
        colacc.w += wh1*a[j].w + wh2*bb[j].w;
    }

    // ---- products
    float4 p[4];
    #pragma unroll
    for (int j = 0; j < 4; ++j) {
        p[j].x = a[j].x*bb[j].x; p[j].y = a[j].y*bb[j].y;
        p[j].z = a[j].z*bb[j].z; p[j].w = a[j].w*bb[j].w;
    }
    const float em = ((top && r0 == 0) || (bot && r0 == 60)) ? 0.f : 1.f;
    float4 pe;
    pe.x = ea.x*eb.x*em; pe.y = ea.y*eb.y*em;
    pe.z = ea.z*eb.z*em; pe.w = ea.w*eb.w*em;

    // ---- vertical halo exchange via LDS
    xch[rg][0][lane] = p[0];
    xch[rg][1][lane] = p[3];
    __syncthreads();
    float4 pm1, pp4;
    if (top) pm1 = pe; else pm1 = xch[rg-1][1][lane];
    if (bot) pp4 = pe; else pp4 = xch[rg+1][0][lane];

    // ---- vertical 3-tap (registers)
    float4 v[4];
    v[0].x = pm1.x + p[0].x + p[1].x; v[0].y = pm1.y + p[0].y + p[1].y;
    v[0].z = pm1.z + p[0].z + p[1].z; v[0].w = pm1.w + p[0].w + p[1].w;
    v[1].x = p[0].x + p[1].x + p[2].x; v[1].y = p[0].y + p[1].y + p[2].y;
    v[1].z = p[0].z + p[1].z + p[2].z; v[1].w = p[0].w + p[1].w + p[2].w;
    v[2].x = p[1].x + p[2].x + p[3].x; v[2].y = p[1].y + p[2].y + p[3].y;
    v[2].z = p[1].z + p[2].z + p[3].z; v[2].w = p[1].w + p[2].w + p[3].w;
    v[3].x = p[2].x + p[3].x + pp4.x; v[3].y = p[2].y + p[3].y + pp4.y;
    v[3].z = p[2].z + p[3].z + pp4.z; v[3].w = p[2].w + p[3].w + pp4.w;

    // ---- horizontal 3-tap (neighbor col = lane +-4) + abs
    float4 c4[4];
    #pragma unroll
    for (int i = 0; i < 4; ++i) {
        float L = __shfl_up(v[i].w, 4);
        float R = __shfl_down(v[i].x, 4);
        if (fc == 0)  L = 0.f;
        if (fc == 15) R = 0.f;
        c4[i].x = fabsf(L      + v[i].x + v[i].y);
        c4[i].y = fabsf(v[i].x + v[i].y + v[i].z);
        c4[i].z = fabsf(v[i].y + v[i].z + v[i].w);
        c4[i].w = fabsf(v[i].z + v[i].w + R);
    }

    // ---- reduce over the 4 pair-lanes, then atomics into cons
    #pragma unroll
    for (int i = 0; i < 4; ++i) {
        c4[i].x += __shfl_xor(c4[i].x, 1); c4[i].x += __shfl_xor(c4[i].x, 2);
        c4[i].y += __shfl_xor(c4[i].y, 1); c4[i].y += __shfl_xor(c4[i].y, 2);
        c4[i].z += __shfl_xor(c4[i].z, 1); c4[i].z += __shfl_xor(c4[i].z, 2);
        c4[i].w += __shfl_xor(c4[i].w, 1); c4[i].w += __shfl_xor(c4[i].w, 2);
    }
    float* gh   = ws + WS_GH;
    float* gw   = ws + WS_GW;
    float* cons = ws + WS_CONS;
    const float SC = 1.0f/(9.0f*128.0f);
    if (pl == 0) {
        #pragma unroll
        for (int i = 0; i < 4; ++i) {
            float* cp = &cons[((size_t)(b*NH) + r0 + i)*NW + (fc << 2)];
            atomicAdd(cp + 0, c4[i].x * SC);
            atomicAdd(cp + 1, c4[i].y * SC);
            atomicAdd(cp + 2, c4[i].z * SC);
            atomicAdd(cp + 3, c4[i].w * SC);
        }
    }

    // ---- gh: full-wave reduce per owned row
    #pragma unroll
    for (int k = 0; k < 4; ++k) {
        float s = ghrow[k];
        s += __shfl_xor(s, 1);  s += __shfl_xor(s, 2);
        s += __shfl_xor(s, 4);  s += __shfl_xor(s, 8);
        s += __shfl_xor(s, 16); s += __shfl_xor(s, 32);
        if (lane == 0) atomicAdd(&gh[b*NH + r0 + k], s * (1.0f/16384.0f));
    }

    // ---- gw: reduce colacc over pairs (shfl) then over the 4 waves (LDS)
    colacc.x += __shfl_xor(colacc.x, 1); colacc.x += __shfl_xor(colacc.x, 2);
    colacc.y += __shfl_xor(colacc.y, 1); colacc.y += __shfl_xor(colacc.y, 2);
    colacc.z += __shfl_xor(colacc.z, 1); colacc.z += __shfl_xor(colacc.z, 2);
    colacc.w += __shfl_xor(colacc.w, 1); colacc.w += __shfl_xor(colacc.w, 2);
    if (pl == 0) ldsc[rg][fc] = colacc;
    __syncthreads();
    if (t < 16) {
        float4 s0 = ldsc[0][t], s1 = ldsc[1][t], s2 = ldsc[2][t], s3 = ldsc[3][t];
        float4 s;
        s.x = (s0.x+s1.x)+(s2.x+s3.x);
        s.y = (s0.y+s1.y)+(s2.y+s3.y);
        s.z = (s0.z+s1.z)+(s2.z+s3.z);
        s.w = (s0.w+s1.w)+(s2.w+s3.w);
        float* g = &gw[b*NW + t*4];
        atomicAdd(g+0, s.x * (1.0f/16384.0f));
        atomicAdd(g+1, s.y * (1.0f/16384.0f));
        atomicAdd(g+2, s.z * (1.0f/16384.0f));
        atomicAdd(g+3, s.w * (1.0f/16384.0f));
    }
}

// fused attention + apply (R3-proven ~12us, x is L3-resident on this pass)
__global__ __launch_bounds__(256) void k_apply(const float* __restrict__ x,
                                               const float* __restrict__ ws,
                                               const float* __restrict__ pgw,
                                               const float* __restrict__ pgb,
                                               float* __restrict__ out) {
    const float gateW = pgw[0];
    const float gateB = pgb[0];
    const float* gh   = ws + WS_GH;
    const float* gw   = ws + WS_GW;
    const float* cons = ws + WS_CONS;
    const long total4 = (long)NB*NC*NH*NW/4;   // 4,194,304
    const long stride = (long)gridDim.x * blockDim.x;
    for (long i = (long)blockIdx.x*blockDim.x + threadIdx.x; i < total4; i += stride) {
        const long e = i << 2;
        const int w = (int)(e & 63);            // multiple of 4
        const int h = (int)((e >> 6) & 63);
        const int b = (int)(e >> 20);           // C*H*W = 2^20

        const float4 xv  = reinterpret_cast<const float4*>(x)[i];
        const float4 cv  = *reinterpret_cast<const float4*>(&cons[((b<<6) + h)*64 + w]);
        const float4 gwv = *reinterpret_cast<const float4*>(&gw[(b<<6) + w]);
        const float ghv  = gh[(b<<6) + h];

        float4 o;
        float z;
        z = gateW * (ghv + gwv.x) * (1.f - fminf(fmaxf(cv.x, 0.f), 1.f)) + gateB;
        o.x = xv.x / (1.f + expf(-z));
        z = gateW * (ghv + gwv.y) * (1.f - fminf(fmaxf(cv.y, 0.f), 1.f)) + gateB;
        o.y = xv.y / (1.f + expf(-z));
        z = gateW * (ghv + gwv.z) * (1.f - fminf(fmaxf(cv.z, 0.f), 1.f)) + gateB;
        o.z = xv.z / (1.f + expf(-z));
        z = gateW * (ghv + gwv.w) * (1.f - fminf(fmaxf(cv.w, 0.f), 1.f)) + gateB;
        o.w = xv.w / (1.f + expf(-z));
        reinterpret_cast<float4*>(out)[i] = o;
    }
}

extern "C" void kernel_launch(void* const* d_in, const int* in_sizes, int n_in,
                              void* d_out, int out_size, void* d_ws, size_t ws_size,
                              hipStream_t stream) {
    const float* x   = (const float*)d_in[0];
    const float* dwh = (const float*)d_in[1];
    const float* dww = (const float*)d_in[2];
    const float* pgw = (const float*)d_in[3];
    const float* pgb = (const float*)d_in[4];
    float* out = (float*)d_out;
    float* ws  = (float*)d_ws;

    k_init<<<67, 256, 0, stream>>>(dwh, dww, ws);
    k_reduce<<<NB*4*32, 256, 0, stream>>>(x, ws);
    k_apply<<<2048, 256, 0, stream>>>(x, ws, pgw, pgb, out);
}

// Round 8
// 55.039 us; speedup vs baseline: 1.6256x; 1.6256x over previous
//
#include <hip/hip_runtime.h>
#include <math.h>

#define NB 16
#define NC 256
#define NH 64
#define NW 64
#define HALF 128
#define PLANE (NH*NW)   // 4096

// ws float layout
#define WS_WW   0       // 256: softmax(dir_weight_w)
#define WS_WH   256     // 256: softmax(dir_weight_h)
#define WS_ATT  512     // NB*NH*NW = 65536
#define WS_TOTAL 66048

// d_out scratch layout (floats). All plain stores, no atomics.
// cons slices: 32 slices x 65536 floats = 2,097,152
#define SCR_GHP 2097152   // [b*64+h]*32 + pg            : 32768 floats
#define SCR_GWP 2129920   // [j]*1024 + b*64 + w (j=stripe*32+pg) : 131072 floats

__device__ __forceinline__ float sum4(float4 v) { return (v.x+v.y)+(v.z+v.w); }

// single block: both channel softmaxes
__global__ __launch_bounds__(256) void k_init(const float* __restrict__ dwh,
                                              const float* __restrict__ dww,
                                              float* __restrict__ ws) {
    __shared__ float red[256];
    const int t = threadIdx.x;
    const float vh = dwh[t];
    const float vw = dww[t];

    red[t] = vw; __syncthreads();
    for (int s = 128; s > 0; s >>= 1) { if (t < s) red[t] = fmaxf(red[t], red[t+s]); __syncthreads(); }
    const float mw = red[0]; __syncthreads();
    const float ew = expf(vw - mw);
    red[t] = ew; __syncthreads();
    for (int s = 128; s > 0; s >>= 1) { if (t < s) red[t] += red[t+s]; __syncthreads(); }
    const float sw = red[0]; __syncthreads();
    ws[WS_WW + t] = ew / sw;

    red[t] = vh; __syncthreads();
    for (int s = 128; s > 0; s >>= 1) { if (t < s) red[t] = fmaxf(red[t], red[t+s]); __syncthreads(); }
    const float mh = red[0]; __syncthreads();
    const float eh = expf(vh - mh);
    red[t] = eh; __syncthreads();
    for (int s = 128; s > 0; s >>= 1) { if (t < s) red[t] += red[t+s]; __syncthreads(); }
    const float sh = red[0]; __syncthreads();
    ws[WS_WH + t] = eh / sh;
}

// Block = (b, 16-row stripe, group of 4 channel pairs). 2048 blocks.
// Wave = row-group (4 rows). Lane = fc(4b)<<2 | pl(2b).
// R6 compute core; ALL outputs are plain per-block partial stores (no atomics).
__global__ __launch_bounds__(256) void k_reduce(const float* __restrict__ x,
                                                const float* __restrict__ ws,
                                                float* __restrict__ scr) {
    __shared__ float4 ldsc[4][16];   // gw staging, 1 KB

    const int t    = threadIdx.x;
    const int rg   = t >> 6;        // wave id = row group 0..3
    const int lane = t & 63;
    const int pl   = lane & 3;      // channel-pair lane
    const int fc   = lane >> 2;     // float4 col 0..15

    const int blk    = blockIdx.x;
    const int pg     = blk & 31;
    const int stripe = (blk >> 5) & 3;
    const int b      = blk >> 7;

    const int c1 = pg*4 + pl;
    const int c2 = c1 + HALF;
    const int r0 = stripe*16 + rg*4;     // first owned row

    const float ww1 = ws[WS_WW + c1], ww2 = ws[WS_WW + c2];
    const float wh1 = ws[WS_WH + c1], wh2 = ws[WS_WH + c2];

    const float* p1 = x + ((size_t)(b*NC + c1)) * PLANE;
    const float* p2 = x + ((size_t)(b*NC + c2)) * PLANE;

    // 12 independent float4 loads: rows r0-1 .. r0+4 (clamped), cols 4fc..4fc+3
    float4 a[6], bb[6];
    #pragma unroll
    for (int j = 0; j < 6; ++j) {
        int r = r0 - 1 + j;
        r = (r < 0) ? 0 : (r > 63 ? 63 : r);
        a[j]  = *(reinterpret_cast<const float4*>(p1 + r*NW) + fc);
        bb[j] = *(reinterpret_cast<const float4*>(p2 + r*NW) + fc);
    }

    // gh / gw contributions from owned rows (j=1..4 -> rows r0..r0+3)
    float ghrow[4];
    float4 colacc = {0.f,0.f,0.f,0.f};
    #pragma unroll
    for (int j = 1; j <= 4; ++j) {
        ghrow[j-1] = ww1*sum4(a[j]) + ww2*sum4(bb[j]);
        colacc.x += wh1*a[j].x + wh2*bb[j].x;
        colacc.y += wh1*a[j].y + wh2*bb[j].y;
        colacc.z += wh1*a[j].z + wh2*bb[j].z;
        colacc.w += wh1*a[j].w + wh2*bb[j].w;
    }

    // products, zero-pad masks at global top/bottom rows
    const float km0 = (r0 == 0)  ? 0.f : 1.f;
    const float km5 = (r0 == 60) ? 0.f : 1.f;
    float4 p[6];
    #pragma unroll
    for (int j = 0; j < 6; ++j) {
        p[j].x = a[j].x*bb[j].x; p[j].y = a[j].y*bb[j].y;
        p[j].z = a[j].z*bb[j].z; p[j].w = a[j].w*bb[j].w;
    }
    p[0].x *= km0; p[0].y *= km0; p[0].z *= km0; p[0].w *= km0;
    p[5].x *= km5; p[5].y *= km5; p[5].z *= km5; p[5].w *= km5;

    // vertical 3-tap in registers; horizontal 3-tap: neighbor col = lane +-4
    float4 c4[4];
    #pragma unroll
    for (int i = 0; i < 4; ++i) {
        float4 v;
        v.x = p[i].x + p[i+1].x + p[i+2].x;
        v.y = p[i].y + p[i+1].y + p[i+2].y;
        v.z = p[i].z + p[i+1].z + p[i+2].z;
        v.w = p[i].w + p[i+1].w + p[i+2].w;
        float L = __shfl_up(v.w, 4);
        float R = __shfl_down(v.x, 4);
        if (fc == 0)  L = 0.f;
        if (fc == 15) R = 0.f;
        c4[i].x = fabsf(L      + v.x + v.y);
        c4[i].y = fabsf(v.x + v.y + v.z);
        c4[i].z = fabsf(v.y + v.z + v.w);
        c4[i].w = fabsf(v.z + v.w + R);
    }

    // cons: reduce over the 4 pair-lanes via shfl, store slice partial
    const float SC = 1.0f/(9.0f*128.0f);
    #pragma unroll
    for (int i = 0; i < 4; ++i) {
        c4[i].x += __shfl_xor(c4[i].x, 1); c4[i].x += __shfl_xor(c4[i].x, 2);
        c4[i].y += __shfl_xor(c4[i].y, 1); c4[i].y += __shfl_xor(c4[i].y, 2);
        c4[i].z += __shfl_xor(c4[i].z, 1); c4[i].z += __shfl_xor(c4[i].z, 2);
        c4[i].w += __shfl_xor(c4[i].w, 1); c4[i].w += __shfl_xor(c4[i].w, 2);
    }
    if (pl == 0) {
        // slice pg: [b][stripe-region 16x64] pixel-linear (f4 units)
        float4* dst = reinterpret_cast<float4*>(scr) + ((size_t)pg << 14) + ((b*4 + stripe) << 8);
        #pragma unroll
        for (int i = 0; i < 4; ++i) {
            float4 s = { c4[i].x*SC, c4[i].y*SC, c4[i].z*SC, c4[i].w*SC };
            dst[(rg*4 + i)*16 + fc] = s;
        }
    }

    // gh: full-wave reduce per owned row -> one partial store per row
    #pragma unroll
    for (int k = 0; k < 4; ++k) {
        float s = ghrow[k];
        s += __shfl_xor(s, 1);  s += __shfl_xor(s, 2);
        s += __shfl_xor(s, 4);  s += __shfl_xor(s, 8);
        s += __shfl_xor(s, 16); s += __shfl_xor(s, 32);
        if (lane == 0)
            scr[SCR_GHP + (b*NH + r0 + k)*32 + pg] = s * (1.0f/16384.0f);
    }

    // gw: reduce colacc over pairs (shfl) then over the 4 waves (LDS), store
    colacc.x += __shfl_xor(colacc.x, 1); colacc.x += __shfl_xor(colacc.x, 2);
    colacc.y += __shfl_xor(colacc.y, 1); colacc.y += __shfl_xor(colacc.y, 2);
    colacc.z += __shfl_xor(colacc.z, 1); colacc.z += __shfl_xor(colacc.z, 2);
    colacc.w += __shfl_xor(colacc.w, 1); colacc.w += __shfl_xor(colacc.w, 2);
    if (pl == 0) ldsc[rg][fc] = colacc;
    __syncthreads();
    if (t < 16) {
        float4 s0 = ldsc[0][t], s1 = ldsc[1][t], s2 = ldsc[2][t], s3 = ldsc[3][t];
        float4 s;
        s.x = ((s0.x+s1.x)+(s2.x+s3.x)) * (1.0f/16384.0f);
        s.y = ((s0.y+s1.y)+(s2.y+s3.y)) * (1.0f/16384.0f);
        s.z = ((s0.z+s1.z)+(s2.z+s3.z)) * (1.0f/16384.0f);
        s.w = ((s0.w+s1.w)+(s2.w+s3.w)) * (1.0f/16384.0f);
        *reinterpret_cast<float4*>(scr + SCR_GWP + (size_t)(stripe*32 + pg)*1024 + b*NW + t*4) = s;
    }
}

// 64 blocks: block = (b, quarter). Reduce gh/gw partials into LDS, then
// att = sigmoid(gate) per pixel (1 float4-pixel per thread).
__global__ __launch_bounds__(256) void k_att(float* __restrict__ ws,
                                             const float* __restrict__ scr,
                                             const float* __restrict__ pgw,
                                             const float* __restrict__ pgb) {
    __shared__ __align__(16) float sgh[64];
    __shared__ __align__(16) float sgw[64];
    const int t = threadIdx.x;
    const int b = blockIdx.x >> 2;
    const int q = blockIdx.x & 3;

    if (t < 64) {
        float acc = 0.f;
        for (int j = 0; j < 128; ++j) acc += scr[SCR_GWP + (size_t)j*1024 + b*NW + t];
        sgw[t] = acc;
    } else if (t < 128) {
        const int r = t - 64;
        float acc = 0.f;
        const float* g = scr + SCR_GHP + (b*NH + r)*32;
        for (int pg = 0; pg < 32; ++pg) acc += g[pg];
        sgh[r] = acc;
    }
    __syncthreads();

    const int u  = (b << 10) + (q << 8) + t;   // float4-pixel 0..16383
    const float4* cp = reinterpret_cast<const float4*>(scr);
    float4 s = {0.f,0.f,0.f,0.f};
    #pragma unroll
    for (int g = 0; g < 32; ++g) {
        const float4 v = cp[((size_t)g << 14) + u];
        s.x += v.x; s.y += v.y; s.z += v.z; s.w += v.w;
    }
    const int h  = (u >> 4) & 63;
    const int w4 = u & 15;
    const float ghv  = sgh[h];
    const float4 gwv = *reinterpret_cast<const float4*>(&sgw[w4*4]);
    const float gW = pgw[0], gB = pgb[0];

    float4 o;
    float z;
    z = gW*(ghv+gwv.x)*(1.f - fminf(fmaxf(s.x,0.f),1.f)) + gB; o.x = 1.f/(1.f+expf(-z));
    z = gW*(ghv+gwv.y)*(1.f - fminf(fmaxf(s.y,0.f),1.f)) + gB; o.y = 1.f/(1.f+expf(-z));
    z = gW*(ghv+gwv.z)*(1.f - fminf(fmaxf(s.z,0.f),1.f)) + gB; o.z = 1.f/(1.f+expf(-z));
    z = gW*(ghv+gwv.w)*(1.f - fminf(fmaxf(s.w,0.f),1.f)) + gB; o.w = 1.f/(1.f+expf(-z));
    reinterpret_cast<float4*>(ws + WS_ATT)[u] = o;
}

__global__ __launch_bounds__(256) void k_apply(const float* __restrict__ x,
                                               const float* __restrict__ ws,
                                               float* __restrict__ out) {
    const float* att = ws + WS_ATT;
    const int total4 = NB*NC*NH*NW/4;   // 4,194,304
    const int stride = gridDim.x * blockDim.x;
    for (int i = blockIdx.x*blockDim.x + threadIdx.x; i < total4; i += stride) {
        const int w4 = i & 15;
        const int h  = (i >> 4) & 63;
        const int b  = i >> 18;
        const float4 xv = reinterpret_cast<const float4*>(x)[i];
        const float4 av = reinterpret_cast<const float4*>(att)[(b << 10) + (h << 4) + w4];
        float4 o;
        o.x = xv.x*av.x; o.y = xv.y*av.y; o.z = xv.z*av.z; o.w = xv.w*av.w;
        reinterpret_cast<float4*>(out)[i] = o;
    }
}

extern "C" void kernel_launch(void* const* d_in, const int* in_sizes, int n_in,
                              void* d_out, int out_size, void* d_ws, size_t ws_size,
                              hipStream_t stream) {
    const float* x   = (const float*)d_in[0];
    const float* dwh = (const float*)d_in[1];
    const float* dww = (const float*)d_in[2];
    const float* pgw = (const float*)d_in[3];
    const float* pgb = (const float*)d_in[4];
    float* out = (float*)d_out;
    float* ws  = (float*)d_ws;
    // d_out doubles as scratch for all reduce partials (~8.6 MB): written by
    // k_reduce, consumed by k_att, then fully overwritten by k_apply.
    float* scr = out;

    k_init<<<1, 256, 0, stream>>>(dwh, dww, ws);
    k_reduce<<<NB*4*32, 256, 0, stream>>>(x, ws, scr);
    k_att<<<64, 256, 0, stream>>>(ws, scr, pgw, pgb);
    k_apply<<<2048, 256, 0, stream>>>(x, ws, out);
}

// Round 9
// 54.332 us; speedup vs baseline: 1.6468x; 1.0130x over previous
//
#include <hip/hip_runtime.h>
#include <math.h>

#define NB 16
#define NC 256
#define NH 64
#define NW 64
#define HALF 128
#define PLANE (NH*NW)   // 4096

// ws float layout
#define WS_WW   0       // 256: softmax(dir_weight_w)
#define WS_WH   256     // 256: softmax(dir_weight_h)
#define WS_ATT  512     // NB*NH*NW = 65536
#define WS_TOTAL 66048

// d_out scratch layout (floats). All plain stores, no atomics.
// cons slices: 32 slices x 65536 floats = 2,097,152
#define SCR_GHP 2097152   // [b*64+h]*32 + pg : 32768 floats
#define SCR_GWP 2129920   // [j]*1024 + b*64 + w (j=stripe*32+pg) : 131072 floats

typedef __attribute__((address_space(1))) void gvoid;
typedef __attribute__((address_space(3))) void lvoid;

// async global->LDS, 16B per lane; LDS dest = uniform base + lane*16
__device__ __forceinline__ void async_load16(const float* g, float* l) {
    __builtin_amdgcn_global_load_lds((gvoid*)(size_t)(const void*)g, (lvoid*)l, 16, 0, 0);
}

__device__ __forceinline__ float sum4(float4 v) { return (v.x+v.y)+(v.z+v.w); }

// single block: both channel softmaxes
__global__ __launch_bounds__(256) void k_init(const float* __restrict__ dwh,
                                              const float* __restrict__ dww,
                                              float* __restrict__ ws) {
    __shared__ float red[256];
    const int t = threadIdx.x;
    const float vh = dwh[t];
    const float vw = dww[t];

    red[t] = vw; __syncthreads();
    for (int s = 128; s > 0; s >>= 1) { if (t < s) red[t] = fmaxf(red[t], red[t+s]); __syncthreads(); }
    const float mw = red[0]; __syncthreads();
    const float ew = expf(vw - mw);
    red[t] = ew; __syncthreads();
    for (int s = 128; s > 0; s >>= 1) { if (t < s) red[t] += red[t+s]; __syncthreads(); }
    const float sw = red[0]; __syncthreads();
    ws[WS_WW + t] = ew / sw;

    red[t] = vh; __syncthreads();
    for (int s = 128; s > 0; s >>= 1) { if (t < s) red[t] = fmaxf(red[t], red[t+s]); __syncthreads(); }
    const float mh = red[0]; __syncthreads();
    const float eh = expf(vh - mh);
    red[t] = eh; __syncthreads();
    for (int s = 128; s > 0; s >>= 1) { if (t < s) red[t] += red[t+s]; __syncthreads(); }
    const float sh = red[0]; __syncthreads();
    ws[WS_WH + t] = eh / sh;
}

// Block = (b, 16-row stripe, group of 4 channel pairs). 2048 blocks.
// Wave = row-group rg (4 rows). Lane = fc(4b)<<2 | pl(2b).
// Staging: wave rg issues 8 async global_load_lds (its 4 rows x 2 plane
// halves, 1024B each) -- no VGPRs held, deep MLP. Source is pre-swizzled so
// LDS slot = lane = fc*4+pl; compute reads are consecutive-lane ds_read_b128.
// Stripe-halo rows (2) -> registers on edge waves. R8's no-atomic epilogue.
__global__ __launch_bounds__(256) void k_reduce(const float* __restrict__ x,
                                                const float* __restrict__ ws,
                                                float* __restrict__ scr) {
    __shared__ float stage[32*256];   // 32 units x 1024B = 32 KB
    __shared__ float4 ldsc[4][16];    // gw staging, 1 KB

    const int t    = threadIdx.x;
    const int rg   = t >> 6;        // wave id = row group 0..3
    const int lane = t & 63;
    const int pl   = lane & 3;      // channel-pair lane
    const int fc   = lane >> 2;     // float4 col 0..15

    const int blk    = blockIdx.x;
    const int pg     = blk & 31;
    const int stripe = (blk >> 5) & 3;
    const int b      = blk >> 7;

    const int r0s = stripe * 16;    // stripe first row
    const int r0  = r0s + rg*4;     // thread's first owned row

    // ---- async staging: unit u = lr*2 + ph; slot within unit = fc*4+pl = lane
    {
        const size_t bbase = (size_t)b * NC * PLANE;
        #pragma unroll
        for (int i = 0; i < 8; ++i) {
            const int u  = rg*8 + i;
            const int lr = u >> 1;
            const int ph = u & 1;
            const int ch = pg*4 + pl + ph*HALF;
            const float* src = x + bbase + (size_t)ch*PLANE + (r0s + lr)*NW + fc*4;
            async_load16(src, &stage[u*256]);
        }
    }

    // ---- stripe-halo rows -> registers (edge waves only, wave-uniform branch)
    float4 ea = {0.f,0.f,0.f,0.f}, eb = {0.f,0.f,0.f,0.f};
    if (rg == 0 || rg == 3) {
        int er = (rg == 0) ? r0s - 1 : r0s + 16;
        er = er < 0 ? 0 : (er > 63 ? 63 : er);
        const int c1 = pg*4 + pl;
        ea = *(reinterpret_cast<const float4*>(x + ((size_t)(b*NC + c1)) * PLANE + er*NW) + fc);
        eb = *(reinterpret_cast<const float4*>(x + ((size_t)(b*NC + c1 + HALF)) * PLANE + er*NW) + fc);
    }

    const float ww1 = ws[WS_WW + pg*4 + pl], ww2 = ws[WS_WW + pg*4 + pl + HALF];
    const float wh1 = ws[WS_WH + pg*4 + pl], wh2 = ws[WS_WH + pg*4 + pl + HALF];

    __syncthreads();   // drains vmcnt(0) (async loads) + barrier

    // ---- gather rows r0-1 .. r0+4 from LDS (halo edges from registers)
    const float4* st4 = reinterpret_cast<const float4*>(stage);
    float4 a[6], bb[6];
    #pragma unroll
    for (int j = 0; j < 6; ++j) {
        const int lr = rg*4 - 1 + j;
        if (lr < 0 || lr > 15) { a[j] = ea; bb[j] = eb; }
        else { a[j] = st4[(lr*2 + 0)*64 + lane]; bb[j] = st4[(lr*2 + 1)*64 + lane]; }
    }

    // gh / gw contributions from owned rows (j=1..4 -> rows r0..r0+3)
    float ghrow[4];
    float4 colacc = {0.f,0.f,0.f,0.f};
    #pragma unroll
    for (int j = 1; j <= 4; ++j) {
        ghrow[j-1] = ww1*sum4(a[j]) + ww2*sum4(bb[j]);
        colacc.x += wh1*a[j].x + wh2*bb[j].x;
        colacc.y += wh1*a[j].y + wh2*bb[j].y;
        colacc.z += wh1*a[j].z + wh2*bb[j].z;
        colacc.w += wh1*a[j].w + wh2*bb[j].w;
    }

    // products, zero-pad masks at global top/bottom rows
    const float km0 = (r0 == 0)  ? 0.f : 1.f;
    const float km5 = (r0 == 60) ? 0.f : 1.f;
    float4 p[6];
    #pragma unroll
    for (int j = 0; j < 6; ++j) {
        p[j].x = a[j].x*bb[j].x; p[j].y = a[j].y*bb[j].y;
        p[j].z = a[j].z*bb[j].z; p[j].w = a[j].w*bb[j].w;
    }
    p[0].x *= km0; p[0].y *= km0; p[0].z *= km0; p[0].w *= km0;
    p[5].x *= km5; p[5].y *= km5; p[5].z *= km5; p[5].w *= km5;

    // vertical 3-tap in registers; horizontal 3-tap: neighbor col = lane +-4
    float4 c4[4];
    #pragma unroll
    for (int i = 0; i < 4; ++i) {
        float4 v;
        v.x = p[i].x + p[i+1].x + p[i+2].x;
        v.y = p[i].y + p[i+1].y + p[i+2].y;
        v.z = p[i].z + p[i+1].z + p[i+2].z;
        v.w = p[i].w + p[i+1].w + p[i+2].w;
        float L = __shfl_up(v.w, 4);
        float R = __shfl_down(v.x, 4);
        if (fc == 0)  L = 0.f;
        if (fc == 15) R = 0.f;
        c4[i].x = fabsf(L      + v.x + v.y);
        c4[i].y = fabsf(v.x + v.y + v.z);
        c4[i].z = fabsf(v.y + v.z + v.w);
        c4[i].w = fabsf(v.z + v.w + R);
    }

    // cons: reduce over the 4 pair-lanes via shfl, store slice partial
    const float SC = 1.0f/(9.0f*128.0f);
    #pragma unroll
    for (int i = 0; i < 4; ++i) {
        c4[i].x += __shfl_xor(c4[i].x, 1); c4[i].x += __shfl_xor(c4[i].x, 2);
        c4[i].y += __shfl_xor(c4[i].y, 1); c4[i].y += __shfl_xor(c4[i].y, 2);
        c4[i].z += __shfl_xor(c4[i].z, 1); c4[i].z += __shfl_xor(c4[i].z, 2);
        c4[i].w += __shfl_xor(c4[i].w, 1); c4[i].w += __shfl_xor(c4[i].w, 2);
    }
    if (pl == 0) {
        float4* dst = reinterpret_cast<float4*>(scr) + ((size_t)pg << 14) + ((b*4 + stripe) << 8);
        #pragma unroll
        for (int i = 0; i < 4; ++i) {
            float4 s = { c4[i].x*SC, c4[i].y*SC, c4[i].z*SC, c4[i].w*SC };
            dst[(rg*4 + i)*16 + fc] = s;
        }
    }

    // gh: full-wave reduce per owned row -> one partial store per row
    #pragma unroll
    for (int k = 0; k < 4; ++k) {
        float s = ghrow[k];
        s += __shfl_xor(s, 1);  s += __shfl_xor(s, 2);
        s += __shfl_xor(s, 4);  s += __shfl_xor(s, 8);
        s += __shfl_xor(s, 16); s += __shfl_xor(s, 32);
        if (lane == 0)
            scr[SCR_GHP + (b*NH + r0 + k)*32 + pg] = s * (1.0f/16384.0f);
    }

    // gw: reduce colacc over pairs (shfl) then over the 4 waves (LDS), store
    colacc.x += __shfl_xor(colacc.x, 1); colacc.x += __shfl_xor(colacc.x, 2);
    colacc.y += __shfl_xor(colacc.y, 1); colacc.y += __shfl_xor(colacc.y, 2);
    colacc.z += __shfl_xor(colacc.z, 1); colacc.z += __shfl_xor(colacc.z, 2);
    colacc.w += __shfl_xor(colacc.w, 1); colacc.w += __shfl_xor(colacc.w, 2);
    if (pl == 0) ldsc[rg][fc] = colacc;
    __syncthreads();
    if (t < 16) {
        float4 s0 = ldsc[0][t], s1 = ldsc[1][t], s2 = ldsc[2][t], s3 = ldsc[3][t];
        float4 s;
        s.x = ((s0.x+s1.x)+(s2.x+s3.x)) * (1.0f/16384.0f);
        s.y = ((s0.y+s1.y)+(s2.y+s3.y)) * (1.0f/16384.0f);
        s.z = ((s0.z+s1.z)+(s2.z+s3.z)) * (1.0f/16384.0f);
        s.w = ((s0.w+s1.w)+(s2.w+s3.w)) * (1.0f/16384.0f);
        *reinterpret_cast<float4*>(scr + SCR_GWP + (size_t)(stripe*32 + pg)*1024 + b*NW + t*4) = s;
    }
}

// 64 blocks: block = (b, quarter). Reduce gh/gw partials into LDS, then
// att = sigmoid(gate) per pixel (1 float4-pixel per thread).
__global__ __launch_bounds__(256) void k_att(float* __restrict__ ws,
                                             const float* __restrict__ scr,
                                             const float* __restrict__ pgw,
                                             const float* __restrict__ pgb) {
    __shared__ __align__(16) float sgh[64];
    __shared__ __align__(16) float sgw[64];
    const int t = threadIdx.x;
    const int b = blockIdx.x >> 2;
    const int q = blockIdx.x & 3;

    if (t < 64) {
        float acc = 0.f;
        for (int j = 0; j < 128; ++j) acc += scr[SCR_GWP + (size_t)j*1024 + b*NW + t];
        sgw[t] = acc;
    } else if (t < 128) {
        const int r = t - 64;
        float acc = 0.f;
        const float* g = scr + SCR_GHP + (b*NH + r)*32;
        for (int pg = 0; pg < 32; ++pg) acc += g[pg];
        sgh[r] = acc;
    }
    __syncthreads();

    const int u  = (b << 10) + (q << 8) + t;   // float4-pixel 0..16383
    const float4* cp = reinterpret_cast<const float4*>(scr);
    float4 s = {0.f,0.f,0.f,0.f};
    #pragma unroll
    for (int g = 0; g < 32; ++g) {
        const float4 v = cp[((size_t)g << 14) + u];
        s.x += v.x; s.y += v.y; s.z += v.z; s.w += v.w;
    }
    const int h  = (u >> 4) & 63;
    const int w4 = u & 15;
    const float ghv  = sgh[h];
    const float4 gwv = *reinterpret_cast<const float4*>(&sgw[w4*4]);
    const float gW = pgw[0], gB = pgb[0];

    float4 o;
    float z;
    z = gW*(ghv+gwv.x)*(1.f - fminf(fmaxf(s.x,0.f),1.f)) + gB; o.x = 1.f/(1.f+expf(-z));
    z = gW*(ghv+gwv.y)*(1.f - fminf(fmaxf(s.y,0.f),1.f)) + gB; o.y = 1.f/(1.f+expf(-z));
    z = gW*(ghv+gwv.z)*(1.f - fminf(fmaxf(s.z,0.f),1.f)) + gB; o.z = 1.f/(1.f+expf(-z));
    z = gW*(ghv+gwv.w)*(1.f - fminf(fmaxf(s.w,0.f),1.f)) + gB; o.w = 1.f/(1.f+expf(-z));
    reinterpret_cast<float4*>(ws + WS_ATT)[u] = o;
}

__global__ __launch_bounds__(256) void k_apply(const float* __restrict__ x,
                                               const float* __restrict__ ws,
                                               float* __restrict__ out) {
    const float* att = ws + WS_ATT;
    const int total4 = NB*NC*NH*NW/4;   // 4,194,304
    const int stride = gridDim.x * blockDim.x;
    for (int i = blockIdx.x*blockDim.x + threadIdx.x; i < total4; i += stride) {
        const int w4 = i & 15;
        const int h  = (i >> 4) & 63;
        const int b  = i >> 18;
        const float4 xv = reinterpret_cast<const float4*>(x)[i];
        const float4 av = reinterpret_cast<const float4*>(att)[(b << 10) + (h << 4) + w4];
        float4 o;
        o.x = xv.x*av.x; o.y = xv.y*av.y; o.z = xv.z*av.z; o.w = xv.w*av.w;
        reinterpret_cast<float4*>(out)[i] = o;
    }
}

extern "C" void kernel_launch(void* const* d_in, const int* in_sizes, int n_in,
                              void* d_out, int out_size, void* d_ws, size_t ws_size,
                              hipStream_t stream) {
    const float* x   = (const float*)d_in[0];
    const float* dwh = (const float*)d_in[1];
    const float* dww = (const float*)d_in[2];
    const float* pgw = (const float*)d_in[3];
    const float* pgb = (const float*)d_in[4];
    float* out = (float*)d_out;
    float* ws  = (float*)d_ws;
    // d_out doubles as scratch for all reduce partials (~8.6 MB): written by
    // k_reduce, consumed by k_att, then fully overwritten by k_apply.
    float* scr = out;

    k_init<<<1, 256, 0, stream>>>(dwh, dww, ws);
    k_reduce<<<NB*4*32, 256, 0, stream>>>(x, ws, scr);
    k_att<<<64, 256, 0, stream>>>(ws, scr, pgw, pgb);
    k_apply<<<2048, 256, 0, stream>>>(x, ws, out);
}

// Round 10
// 47.315 us; speedup vs baseline: 1.8910x; 1.1483x over previous
//
#include <hip/hip_runtime.h>
#include <math.h>

#define NB 16
#define NC 256
#define NH 64
#define NW 64
#define HALF 128
#define PLANE (NH*NW)   // 4096

#define NT 4                 // tiles per block (4 channel pairs each)
#define UNITS 36             // 18 rows (16 + 2 halo) x 2 plane-halves, 1 KB each
#define TILEF (UNITS*256)    // floats per tile buffer (9216)

// ws: attention map only
#define WS_ATT 0             // NB*NH*NW = 65536 floats

// d_out scratch (floats): 8 cons slices + gh partials + gw partials
#define SCR_GHP 524288             // [b*64+h]*8 + pgc          : 8192 floats
#define SCR_GWP (SCR_GHP + 8192)   // [pgc*4+stripe]*1024 + b*64+w : 32768 floats

typedef __attribute__((address_space(1))) void gvoid;
typedef __attribute__((address_space(3))) void lvoid;

// async global->LDS, 16B/lane; LDS dest = wave-uniform base + lane*16
__device__ __forceinline__ void async_load16(const float* g, float* l) {
    __builtin_amdgcn_global_load_lds((gvoid*)(size_t)(const void*)g, (lvoid*)l, 16, 0, 0);
}

__device__ __forceinline__ float sum4(float4 v) { return (v.x+v.y)+(v.z+v.w); }

// Block = (b, 16-row stripe, chunk of NT=4 pair-groups). 512 blocks (2/CU).
// Wave rg owns rows r0..r0+3; lane = fc(4b)<<2 | pl(2b). Pipelined async
// staging: issue tile k+1 (9 units/wave) -> s_waitcnt vmcnt(9) -> s_barrier ->
// compute tile k from LDS. Halo rows staged too (18 rows/tile). Softmax
// computed in-prologue (no separate init kernel). Epilogue: plain partial
// stores, zero atomics. gh complete per block; cons 8 slices; gw 32 partials.
__global__ __launch_bounds__(256) void k_reduce(const float* __restrict__ x,
                                                const float* __restrict__ dwh,
                                                const float* __restrict__ dww,
                                                float* __restrict__ scr) {
    __shared__ float stage[2*TILEF];          // 72 KB double buffer
    __shared__ float ew[256], eh[256];        // exp(weights)
    __shared__ float wsum[8];                 // wave partial sums (w:0-3, h:4-7)
    __shared__ float4 ldsc[4][16];            // gw cross-wave staging

    const int t    = threadIdx.x;
    const int rg   = t >> 6;       // wave = row group 0..3
    const int lane = t & 63;
    const int pl   = lane & 3;     // channel-pair lane
    const int fc   = lane >> 2;    // float4 col 0..15

    const int blk    = blockIdx.x;
    const int pgc    = blk & 7;          // pair-group chunk 0..7
    const int stripe = (blk >> 3) & 3;
    const int b      = blk >> 5;
    const int r0s    = stripe * 16;
    const int r0     = r0s + rg*4;       // first owned row

    // ---- prologue: exp(weights) + wave partial sums into LDS
    {
        const float vw = dww[t], vh = dwh[t];
        const float evw = expf(vw), evh = expf(vh);
        ew[t] = evw; eh[t] = evh;
        float sw = evw, sh = evh;
        #pragma unroll
        for (int m = 1; m < 64; m <<= 1) { sw += __shfl_xor(sw, m); sh += __shfl_xor(sh, m); }
        if (lane == 0) { wsum[rg] = sw; wsum[4+rg] = sh; }
    }
    // drain: weight loads + softmax LDS writes retired before async sequence
    asm volatile("s_waitcnt vmcnt(0) lgkmcnt(0)" ::: "memory");

    const size_t bbase = (size_t)b * NC * PLANE;
    // ---- issue tile 0
    {
        const int pg = pgc*NT;
        #pragma unroll
        for (int i = 0; i < 9; ++i) {
            const int u = rg*9 + i;
            int gr = r0s + (u >> 1) - 1; gr = gr < 0 ? 0 : (gr > 63 ? 63 : gr);
            const int ch = pg*4 + pl + (u & 1)*HALF;
            async_load16(x + bbase + (size_t)ch*PLANE + gr*NW + fc*4, &stage[u*256]);
        }
    }

    const float km0 = (r0 == 0)  ? 0.f : 1.f;
    const float km5 = (r0 == 60) ? 0.f : 1.f;
    float invSw = 0.f, invSh = 0.f;
    float4 c4[4] = {{0,0,0,0},{0,0,0,0},{0,0,0,0},{0,0,0,0}};
    float  ghrow[4] = {0.f,0.f,0.f,0.f};
    float4 colacc = {0.f,0.f,0.f,0.f};

    for (int k = 0; k < NT; ++k) {
        // own ds ops retired before signaling (closes read-vs-DMA window)
        asm volatile("s_waitcnt lgkmcnt(0)" ::: "memory");
        __builtin_amdgcn_s_barrier();      // all waves done with buf[(k+1)&1]

        if (k == 0) {
            invSw = 1.f / ((wsum[0]+wsum[1]) + (wsum[2]+wsum[3]));
            invSh = 1.f / ((wsum[4]+wsum[5]) + (wsum[6]+wsum[7]));
        }
        if (k < NT-1) {
            const int pg = pgc*NT + k + 1;
            float* dstb = &stage[((k+1)&1)*TILEF];
            #pragma unroll
            for (int i = 0; i < 9; ++i) {
                const int u = rg*9 + i;
                int gr = r0s + (u >> 1) - 1; gr = gr < 0 ? 0 : (gr > 63 ? 63 : gr);
                const int ch = pg*4 + pl + (u & 1)*HALF;
                async_load16(x + bbase + (size_t)ch*PLANE + gr*NW + fc*4, dstb + u*256);
            }
            asm volatile("s_waitcnt vmcnt(9)" ::: "memory");   // tile k landed, k+1 in flight
        } else {
            asm volatile("s_waitcnt vmcnt(0)" ::: "memory");
        }
        __builtin_amdgcn_s_barrier();      // tile k fully staged (all waves)

        // ---- compute tile k
        const int pg = pgc*NT + k;
        const float ww1 = ew[pg*4+pl]      * invSw;
        const float ww2 = ew[pg*4+pl+HALF] * invSw;
        const float wh1 = eh[pg*4+pl]      * invSh;
        const float wh2 = eh[pg*4+pl+HALF] * invSh;

        const float4* st4 = reinterpret_cast<const float4*>(&stage[(k&1)*TILEF]);
        float4 a[6], bv[6];
        #pragma unroll
        for (int j = 0; j < 6; ++j) {
            const int lr = rg*4 + j;       // staged row index (halo offset +1 built in)
            a[j]  = st4[(lr*2+0)*64 + lane];
            bv[j] = st4[(lr*2+1)*64 + lane];
        }

        #pragma unroll
        for (int j = 1; j <= 4; ++j) {
            ghrow[j-1] += ww1*sum4(a[j]) + ww2*sum4(bv[j]);
            colacc.x += wh1*a[j].x + wh2*bv[j].x;
            colacc.y += wh1*a[j].y + wh2*bv[j].y;
            colacc.z += wh1*a[j].z + wh2*bv[j].z;
            colacc.w += wh1*a[j].w + wh2*bv[j].w;
        }

        float4 p[6];
        #pragma unroll
        for (int j = 0; j < 6; ++j) {
            p[j].x = a[j].x*bv[j].x; p[j].y = a[j].y*bv[j].y;
            p[j].z = a[j].z*bv[j].z; p[j].w = a[j].w*bv[j].w;
        }
        p[0].x *= km0; p[0].y *= km0; p[0].z *= km0; p[0].w *= km0;
        p[5].x *= km5; p[5].y *= km5; p[5].z *= km5; p[5].w *= km5;

        #pragma unroll
        for (int i = 0; i < 4; ++i) {
            float4 v;
            v.x = p[i].x + p[i+1].x + p[i+2].x;
            v.y = p[i].y + p[i+1].y + p[i+2].y;
            v.z = p[i].z + p[i+1].z + p[i+2].z;
            v.w = p[i].w + p[i+1].w + p[i+2].w;
            float L = __shfl_up(v.w, 4);
            float R = __shfl_down(v.x, 4);
            if (fc == 0)  L = 0.f;
            if (fc == 15) R = 0.f;
            c4[i].x += fabsf(L   + v.x + v.y);
            c4[i].y += fabsf(v.x + v.y + v.z);
            c4[i].z += fabsf(v.y + v.z + v.w);
            c4[i].w += fabsf(v.z + v.w + R);
        }
    }

    // ---- epilogue (plain stores, no atomics)
    const float SC  = 1.0f/(9.0f*128.0f);
    const float GSC = 1.0f/16384.0f;

    // cons: reduce over 4 pair-lanes -> slice pgc store
    #pragma unroll
    for (int i = 0; i < 4; ++i) {
        c4[i].x += __shfl_xor(c4[i].x, 1); c4[i].x += __shfl_xor(c4[i].x, 2);
        c4[i].y += __shfl_xor(c4[i].y, 1); c4[i].y += __shfl_xor(c4[i].y, 2);
        c4[i].z += __shfl_xor(c4[i].z, 1); c4[i].z += __shfl_xor(c4[i].z, 2);
        c4[i].w += __shfl_xor(c4[i].w, 1); c4[i].w += __shfl_xor(c4[i].w, 2);
    }
    if (pl == 0) {
        float4* dst = reinterpret_cast<float4*>(scr) + (pgc << 14) + (b << 10);
        #pragma unroll
        for (int i = 0; i < 4; ++i) {
            float4 s = { c4[i].x*SC, c4[i].y*SC, c4[i].z*SC, c4[i].w*SC };
            dst[(r0 + i)*16 + fc] = s;
        }
    }

    // gh: full-wave reduce per owned row (complete over this chunk)
    #pragma unroll
    for (int i = 0; i < 4; ++i) {
        float s = ghrow[i];
        s += __shfl_xor(s, 1);  s += __shfl_xor(s, 2);
        s += __shfl_xor(s, 4);  s += __shfl_xor(s, 8);
        s += __shfl_xor(s, 16); s += __shfl_xor(s, 32);
        if (lane == 0) scr[SCR_GHP + (b*NH + r0 + i)*8 + pgc] = s * GSC;
    }

    // gw: reduce over pairs (shfl) then over waves (LDS), partial store
    colacc.x += __shfl_xor(colacc.x, 1); colacc.x += __shfl_xor(colacc.x, 2);
    colacc.y += __shfl_xor(colacc.y, 1); colacc.y += __shfl_xor(colacc.y, 2);
    colacc.z += __shfl_xor(colacc.z, 1); colacc.z += __shfl_xor(colacc.z, 2);
    colacc.w += __shfl_xor(colacc.w, 1); colacc.w += __shfl_xor(colacc.w, 2);
    if (pl == 0) ldsc[rg][fc] = colacc;
    __syncthreads();
    if (t < 16) {
        float4 s0 = ldsc[0][t], s1 = ldsc[1][t], s2 = ldsc[2][t], s3 = ldsc[3][t];
        float4 s;
        s.x = ((s0.x+s1.x)+(s2.x+s3.x)) * GSC;
        s.y = ((s0.y+s1.y)+(s2.y+s3.y)) * GSC;
        s.z = ((s0.z+s1.z)+(s2.z+s3.z)) * GSC;
        s.w = ((s0.w+s1.w)+(s2.w+s3.w)) * GSC;
        *reinterpret_cast<float4*>(scr + SCR_GWP + (size_t)(pgc*4 + stripe)*1024 + b*NW + t*4) = s;
    }
}

// 64 blocks (b, quarter): reduce gh(8)/gw(32) partials, sum 8 cons slices,
// sigmoid -> att map in ws.
__global__ __launch_bounds__(256) void k_att(float* __restrict__ ws,
                                             const float* __restrict__ scr,
                                             const float* __restrict__ pgw,
                                             const float* __restrict__ pgb) {
    __shared__ __align__(16) float sgh[64];
    __shared__ __align__(16) float sgw[64];
    const int t = threadIdx.x;
    const int b = blockIdx.x >> 2;
    const int q = blockIdx.x & 3;

    if (t < 64) {
        float acc = 0.f;
        #pragma unroll 4
        for (int j = 0; j < 32; ++j) acc += scr[SCR_GWP + (size_t)j*1024 + b*NW + t];
        sgw[t] = acc;
    } else if (t < 128) {
        const int r = t - 64;
        float acc = 0.f;
        const float* g = scr + SCR_GHP + (b*NH + r)*8;
        #pragma unroll
        for (int s2 = 0; s2 < 8; ++s2) acc += g[s2];
        sgh[r] = acc;
    }
    __syncthreads();

    const int u = (b << 10) + (q << 8) + t;   // float4-pixel 0..16383
    const float4* cp = reinterpret_cast<const float4*>(scr);
    float4 s = {0.f,0.f,0.f,0.f};
    #pragma unroll
    for (int g = 0; g < 8; ++g) {
        const float4 v = cp[(g << 14) + u];
        s.x += v.x; s.y += v.y; s.z += v.z; s.w += v.w;
    }
    const int h  = (u >> 4) & 63;
    const int w4 = u & 15;
    const float ghv  = sgh[h];
    const float4 gwv = *reinterpret_cast<const float4*>(&sgw[w4*4]);
    const float gW = pgw[0], gB = pgb[0];

    float4 o;
    float z;
    z = gW*(ghv+gwv.x)*(1.f - fminf(fmaxf(s.x,0.f),1.f)) + gB; o.x = 1.f/(1.f+expf(-z));
    z = gW*(ghv+gwv.y)*(1.f - fminf(fmaxf(s.y,0.f),1.f)) + gB; o.y = 1.f/(1.f+expf(-z));
    z = gW*(ghv+gwv.z)*(1.f - fminf(fmaxf(s.z,0.f),1.f)) + gB; o.z = 1.f/(1.f+expf(-z));
    z = gW*(ghv+gwv.w)*(1.f - fminf(fmaxf(s.w,0.f),1.f)) + gB; o.w = 1.f/(1.f+expf(-z));
    reinterpret_cast<float4*>(ws + WS_ATT)[u] = o;
}

__global__ __launch_bounds__(256) void k_apply(const float* __restrict__ x,
                                               const float* __restrict__ ws,
                                               float* __restrict__ out) {
    const float* att = ws + WS_ATT;
    const int total4 = NB*NC*NH*NW/4;   // 4,194,304
    const int stride = gridDim.x * blockDim.x;
    for (int i = blockIdx.x*blockDim.x + threadIdx.x; i < total4; i += stride) {
        const int w4 = i & 15;
        const int h  = (i >> 4) & 63;
        const int b  = i >> 18;
        const float4 xv = reinterpret_cast<const float4*>(x)[i];
        const float4 av = reinterpret_cast<const float4*>(att)[(b << 10) + (h << 4) + w4];
        float4 o;
        o.x = xv.x*av.x; o.y = xv.y*av.y; o.z = xv.z*av.z; o.w = xv.w*av.w;
        reinterpret_cast<float4*>(out)[i] = o;
    }
}

extern "C" void kernel_launch(void* const* d_in, const int* in_sizes, int n_in,
                              void* d_out, int out_size, void* d_ws, size_t ws_size,
                              hipStream_t stream) {
    const float* x   = (const float*)d_in[0];
    const float* dwh = (const float*)d_in[1];
    const float* dww = (const float*)d_in[2];
    const float* pgw = (const float*)d_in[3];
    const float* pgb = (const float*)d_in[4];
    float* out = (float*)d_out;
    float* ws  = (float*)d_ws;
    // d_out doubles as scratch for reduce partials (~2.2 MB): written by
    // k_reduce, consumed by k_att, then fully overwritten by k_apply.
    float* scr = out;

    k_reduce<<<NB*4*8, 256, 0, stream>>>(x, dwh, dww, scr);
    k_att<<<64, 256, 0, stream>>>(ws, scr, pgw, pgb);
    k_apply<<<2048, 256, 0, stream>>>(x, ws, out);
}